// Round 8
// baseline (332.568 us; speedup 1.0000x reference)
//
#include <hip/hip_runtime.h>

// Attention_41601053229865 — fused 3D channel attention, bf16-MFMA, batched.
// B=2, C=192 (4 heads x 48), spatial 32^3 = 32768.
// BISECT: flat-plane dwconv3 (R5-R7, all FAIL 7.611e-2) reverted to the
// 10-plane version from the passing R3-proposal build. Everything else kept
// from R7 (full-coverage atomicAdd gram, aliased workspace).

typedef unsigned short bfr;   // raw bf16 storage

constexpr int C = 192, C3 = 576, S = 32, HEADS = 4, CH = 48;
constexpr long N = 32768;            // 32^3
constexpr long CHN = (long)C3 * N;   // 18,874,368
#define EPSN 1e-12f

using short8 = __attribute__((ext_vector_type(8))) short;
using f32x4  = __attribute__((ext_vector_type(4))) float;

__device__ __forceinline__ float bf2f(bfr h) { return __uint_as_float(((unsigned)h) << 16); }
__device__ __forceinline__ bfr f2bf(float f) {
    unsigned u = __float_as_uint(f);
    return (bfr)((u + 0x7fffu + ((u >> 16) & 1u)) >> 16);
}
__device__ __forceinline__ float ld1(const float* p) { return *p; }
__device__ __forceinline__ float ld1(const bfr* p) { return bf2f(*p); }
__device__ __forceinline__ void st1(float* p, float v) { *p = v; }
__device__ __forceinline__ void st1(bfr* p, float v) { *p = f2bf(v); }
__device__ __forceinline__ float4 ld4(const float* p) { return *reinterpret_cast<const float4*>(p); }
__device__ __forceinline__ float4 ld4(const bfr* p) {
    ushort4 u = *reinterpret_cast<const ushort4*>(p);
    float4 r; r.x = bf2f(u.x); r.y = bf2f(u.y); r.z = bf2f(u.z); r.w = bf2f(u.w); return r;
}
__device__ __forceinline__ void ld8f(const bfr* p, float* o) {
    short8 u = *reinterpret_cast<const short8*>(p);
#pragma unroll
    for (int e = 0; e < 8; ++e) o[e] = bf2f((bfr)u[e]);
}

__device__ __forceinline__ f32x4 mfma16(short8 a, short8 b, f32x4 c) {
    return __builtin_amdgcn_mfma_f32_16x16x32_bf16(a, b, c, 0, 0, 0);
}

// ---------------------------------------------------------------------------
__global__ __launch_bounds__(256) void convert_bf(
    const float* __restrict__ in, bfr* __restrict__ out, int n4)
{
    const int i = blockIdx.x * 256 + threadIdx.x;
    if (i < n4) {
        const float4 v = *reinterpret_cast<const float4*>(in + (long)i * 4);
        ushort4 u;
        u.x = f2bf(v.x); u.y = f2bf(v.y); u.z = f2bf(v.z); u.w = f2bf(v.w);
        *reinterpret_cast<ushort4*>(out + (long)i * 4) = u;
    }
}

// ---------------------------------------------------------------------------
// Transpose [192][N] -> [N][192] bf16. 64x64 tiles; blockIdx.z = batch.
template <typename T>
__global__ __launch_bounds__(256) void transpose_cn(
    const T* __restrict__ in, long in_bstride,
    bfr* __restrict__ outT, long out_bstride)
{
    __shared__ float sh[64][65];
    const T* inb = in + blockIdx.z * in_bstride;
    bfr* outb = outT + blockIdx.z * out_bstride;
    const int c0 = blockIdx.y * 64;
    const long n0 = (long)blockIdx.x * 64;
    for (int i = threadIdx.x; i < 64 * 16; i += 256) {
        const int c = i >> 4, n4 = (i & 15) * 4;
        const float4 v = ld4(inb + (long)(c0 + c) * N + n0 + n4);
        sh[c][n4 + 0] = v.x; sh[c][n4 + 1] = v.y;
        sh[c][n4 + 2] = v.z; sh[c][n4 + 3] = v.w;
    }
    __syncthreads();
    const int n = threadIdx.x >> 2, seg = threadIdx.x & 3;
    bfr* dst = outb + (n0 + n) * 192 + c0 + seg * 16;
#pragma unroll
    for (int g = 0; g < 4; ++g) {
        ushort4 u;
        u.x = f2bf(sh[seg * 16 + g * 4 + 0][n]);
        u.y = f2bf(sh[seg * 16 + g * 4 + 1][n]);
        u.z = f2bf(sh[seg * 16 + g * 4 + 2][n]);
        u.w = f2bf(sh[seg * 16 + g * 4 + 3][n]);
        *reinterpret_cast<ushort4*>(dst + g * 4) = u;
    }
}

// ---------------------------------------------------------------------------
// MFMA GEMM: Y[o][n] = bias[o] + sum_k A[o][k]*BT[n][k], K=192. z = batch.
template <typename TY>
__global__ __launch_bounds__(256) void gemm_mfma(
    const bfr* __restrict__ A, long a_bstride,
    const float* __restrict__ bias,
    const bfr* __restrict__ BT, long bt_bstride,
    TY* __restrict__ Y, long y_bstride,
    int OT)
{
    constexpr int KPAD = 104;
    __shared__ short sA[64][KPAD];
    __shared__ short sB[128][KPAD];
    const bfr* Ab = A + blockIdx.z * a_bstride;
    const bfr* BTb = BT + blockIdx.z * bt_bstride;
    TY* Yb = Y + blockIdx.z * y_bstride;
    const int nwg = gridDim.x;
    const int wg = blockIdx.x;
    const int xcd = wg & 7, lin = wg >> 3;
    const int q = nwg >> 3, r = nwg & 7;
    const int swz = (xcd < r ? xcd * (q + 1) : r * (q + 1) + (xcd - r) * q) + lin;
    const int o0 = (swz % OT) * 64;
    const long n0 = (long)(swz / OT) * 128;
    const int tid = threadIdx.x;
    const int wave = tid >> 6, lane = tid & 63;
    const int wm = wave & 1, wn = wave >> 1;
    const int lr = lane & 15, lk = lane >> 4;

    f32x4 acc[2][4] = {};
    for (int kc = 0; kc < 192; kc += 96) {
        for (int i = tid; i < 64 * 12; i += 256) {
            const int row = i / 12, c8 = (i % 12) * 8;
            *reinterpret_cast<short8*>(&sA[row][c8]) =
                *reinterpret_cast<const short8*>(&Ab[(long)(o0 + row) * 192 + kc + c8]);
        }
        for (int i = tid; i < 128 * 12; i += 256) {
            const int row = i / 12, c8 = (i % 12) * 8;
            *reinterpret_cast<short8*>(&sB[row][c8]) =
                *reinterpret_cast<const short8*>(&BTb[(n0 + row) * 192 + kc + c8]);
        }
        __syncthreads();
#pragma unroll
        for (int ks = 0; ks < 3; ++ks) {
            short8 af[2], bf[4];
#pragma unroll
            for (int mi = 0; mi < 2; ++mi)
                af[mi] = *reinterpret_cast<const short8*>(&sA[wm * 32 + mi * 16 + lr][ks * 32 + lk * 8]);
#pragma unroll
            for (int ni = 0; ni < 4; ++ni)
                bf[ni] = *reinterpret_cast<const short8*>(&sB[wn * 64 + ni * 16 + lr][ks * 32 + lk * 8]);
#pragma unroll
            for (int mi = 0; mi < 2; ++mi)
#pragma unroll
                for (int ni = 0; ni < 4; ++ni)
                    acc[mi][ni] = mfma16(af[mi], bf[ni], acc[mi][ni]);
        }
        __syncthreads();
    }
#pragma unroll
    for (int mi = 0; mi < 2; ++mi) {
#pragma unroll
        for (int j = 0; j < 4; ++j) {
            const int o = o0 + wm * 32 + mi * 16 + lk * 4 + j;
            const float bo = bias[o];
#pragma unroll
            for (int ni = 0; ni < 4; ++ni)
                st1(&Yb[(long)o * N + n0 + wn * 64 + ni * 16 + lr], acc[mi][ni][j] + bo);
        }
    }
}

// ---------------------------------------------------------------------------
// Depthwise 3x3x3 conv + bias, fused q/k sumsq. Block = (ch, 8 h-planes);
// grid (2304, 2). Stages 10 fp32 planes [10][34][38] in LDS, one barrier.
// KNOWN-GOOD version (passed Round-4 bench at absmax 1.2e-3).
__global__ __launch_bounds__(256) void dwconv3(
    const bfr* __restrict__ in, const float* __restrict__ w,
    const float* __restrict__ bias, bfr* __restrict__ out,
    float* __restrict__ sq)
{
    __shared__ float sp[10][34][38];
    const int blk = blockIdx.x;
    const int bb = blockIdx.y;
    const int hg = blk & 3;
    const int ch = blk >> 2;
    const int h0 = hg * 8;
    const bfr* base = in + bb * CHN + (long)ch * N;
    const int tid = threadIdx.x;

    // interior rows: 10 planes x 32 w-rows, vector loads
    for (int r2 = tid; r2 < 320; r2 += 256) {
        const int p = r2 >> 5, ww = r2 & 31;
        const int hh = h0 - 1 + p;
        if (hh >= 0 && hh < 32) {
            const bfr* rp = base + hh * 1024 + ww * 32;
            float vals[32];
            ld8f(rp, vals); ld8f(rp + 8, vals + 8);
            ld8f(rp + 16, vals + 16); ld8f(rp + 24, vals + 24);
#pragma unroll
            for (int e = 0; e < 32; ++e) sp[p][ww + 1][e + 1] = vals[e];
        } else {
#pragma unroll
            for (int e = 0; e < 32; ++e) sp[p][ww + 1][e + 1] = 0.f;
        }
    }
    // halos
    for (int r2 = tid; r2 < 340; r2 += 256) {
        const int p = r2 / 34, a = r2 % 34;
        sp[p][a][0] = 0.f; sp[p][a][33] = 0.f;
        sp[p][0][a] = 0.f; sp[p][33][a] = 0.f;
    }
    float wr[27];
#pragma unroll
    for (int j = 0; j < 27; ++j) wr[j] = w[ch * 27 + j];
    const float bs = bias[ch];
    __syncthreads();

    float ssq = 0.f;
    bfr* outb = out + bb * CHN + (long)ch * N;
#pragma unroll
    for (int t = 0; t < 2; ++t) {
        const int s = tid + t * 256;
        const int p = s >> 6, w0 = ((s >> 3) & 7) * 4, d0 = (s & 7) * 4;
        float acc[4][4];
#pragma unroll
        for (int i = 0; i < 4; ++i)
#pragma unroll
            for (int j = 0; j < 4; ++j) acc[i][j] = bs;
#pragma unroll
        for (int dh = 0; dh < 3; ++dh)
#pragma unroll
            for (int dw2 = 0; dw2 < 3; ++dw2)
#pragma unroll
                for (int dd2 = 0; dd2 < 3; ++dd2) {
                    const float wv = wr[(dh * 3 + dw2) * 3 + dd2];
#pragma unroll
                    for (int i = 0; i < 4; ++i)
#pragma unroll
                        for (int j = 0; j < 4; ++j)
                            acc[i][j] += wv * sp[p + dh][w0 + i + dw2][d0 + j + dd2];
                }
        bfr* op = outb + ((h0 + p) * 32 + w0) * 32 + d0;
#pragma unroll
        for (int i = 0; i < 4; ++i) {
            ushort4 u;
            u.x = f2bf(acc[i][0]); u.y = f2bf(acc[i][1]);
            u.z = f2bf(acc[i][2]); u.w = f2bf(acc[i][3]);
            *reinterpret_cast<ushort4*>(op + i * 32) = u;
#pragma unroll
            for (int j = 0; j < 4; ++j) ssq += acc[i][j] * acc[i][j];
        }
    }
    if (ch < 2 * C) {
#pragma unroll
        for (int off = 32; off > 0; off >>= 1) ssq += __shfl_down(ssq, off, 64);
        __shared__ float wsum[4];
        if ((tid & 63) == 0) wsum[tid >> 6] = ssq;
        __syncthreads();
        if (tid == 0) atomicAdd(&sq[bb * 384 + ch], wsum[0] + wsum[1] + wsum[2] + wsum[3]);
    }
}

// ---------------------------------------------------------------------------
// Gram via MFMA — atomicAdd tail, FULL coverage. grid (512, 2).
__global__ __launch_bounds__(256) void gram_mfma(
    const bfr* __restrict__ qk, float* __restrict__ attn)
{
    __shared__ __align__(16) short sm[2][48][264];
    const int bb = blockIdx.y;
    const int h = blockIdx.x & 3;
    const int chunk = blockIdx.x >> 2;           // 0..127
    const long nbase = (long)chunk * 256;
    const bfr* qb = qk + bb * CHN + (long)(h * CH) * N + nbase;
    const bfr* kb = qk + bb * CHN + (long)(C + h * CH) * N + nbase;
    const int tid = threadIdx.x;
    for (int i = tid; i < 1536; i += 256) {
        const int row = i >> 5, c8 = (i & 31) * 8;
        *reinterpret_cast<short8*>(&sm[0][row][c8]) =
            *reinterpret_cast<const short8*>(qb + (long)row * N + c8);
        *reinterpret_cast<short8*>(&sm[1][row][c8]) =
            *reinterpret_cast<const short8*>(kb + (long)row * N + c8);
    }
    __syncthreads();
    const int wave = tid >> 6, lane = tid & 63;
    const int lr = lane & 15, lk = lane >> 4;
    f32x4 acc[3][3] = {};
#pragma unroll
    for (int w2 = 0; w2 < 2; ++w2) {
        const int ks = wave * 2 + w2;
        short8 aq[3], bk[3];
#pragma unroll
        for (int ct = 0; ct < 3; ++ct)
            aq[ct] = *reinterpret_cast<const short8*>(&sm[0][ct * 16 + lr][ks * 32 + lk * 8]);
#pragma unroll
        for (int et = 0; et < 3; ++et)
            bk[et] = *reinterpret_cast<const short8*>(&sm[1][et * 16 + lr][ks * 32 + lk * 8]);
#pragma unroll
        for (int ct = 0; ct < 3; ++ct)
#pragma unroll
            for (int et = 0; et < 3; ++et)
                acc[ct][et] = mfma16(aq[ct], bk[et], acc[ct][et]);
    }
    float* dst = attn + (long)(bb * HEADS + h) * CH * CH;
#pragma unroll
    for (int ct = 0; ct < 3; ++ct)
#pragma unroll
        for (int et = 0; et < 3; ++et)
#pragma unroll
            for (int j = 0; j < 4; ++j)
                atomicAdd(&dst[(ct * 16 + lk * 4 + j) * CH + et * 16 + lr], acc[ct][et][j]);
}

// ---------------------------------------------------------------------------
__global__ __launch_bounds__(64) void softmax_scale(
    float* __restrict__ attn, const float* __restrict__ sq,
    const float* __restrict__ temp)
{
    const int bb = blockIdx.x >> 2, h = blockIdx.x & 3;
    const int c = threadIdx.x;
    if (c >= CH) return;
    const float* sqb = sq + bb * 384;
    const float invq = 1.0f / fmaxf(sqrtf(sqb[h * CH + c]), EPSN);
    const float t = temp[h];
    float* row = attn + bb * HEADS * CH * CH + ((long)h * CH + c) * CH;
    float vals[CH];
    float mx = -3.4e38f;
#pragma unroll
    for (int e = 0; e < CH; ++e) {
        const float invk = 1.0f / fmaxf(sqrtf(sqb[C + h * CH + e]), EPSN);
        const float v = row[e] * invq * invk * t;
        vals[e] = v;
        mx = fmaxf(mx, v);
    }
    float sum = 0.f;
#pragma unroll
    for (int e = 0; e < CH; ++e) { vals[e] = expf(vals[e] - mx); sum += vals[e]; }
    const float inv = 1.0f / sum;
#pragma unroll
    for (int e = 0; e < CH; ++e) row[e] = vals[e] * inv;
}

// ---------------------------------------------------------------------------
__global__ __launch_bounds__(192) void build_m(
    const float* __restrict__ P, const float* __restrict__ attn,
    bfr* __restrict__ M)
{
    const int bb = blockIdx.y;
    const int o = blockIdx.x;
    const int he = threadIdx.x;
    const int h = he / CH, e = he % CH;
    const float* attb = attn + bb * HEADS * CH * CH;
    float s = 0.f;
#pragma unroll
    for (int cc = 0; cc < CH; ++cc)
        s += P[o * C + h * CH + cc] * attb[((long)h * CH + cc) * CH + e];
    M[(long)bb * C * C + (long)o * C + he] = f2bf(s);
}

// ---------------------------------------------------------------------------
extern "C" void kernel_launch(void* const* d_in, const int* in_sizes, int n_in,
                              void* d_out, int out_size, void* d_ws, size_t ws_size,
                              hipStream_t stream)
{
    const float* x      = (const float*)d_in[0];
    const float* qkv_w  = (const float*)d_in[1];
    const float* qkv_b  = (const float*)d_in[2];
    const float* dw_w   = (const float*)d_in[3];
    const float* dw_b   = (const float*)d_in[4];
    const float* proj_w = (const float*)d_in[5];
    const float* proj_b = (const float*)d_in[6];
    const float* temp   = (const float*)d_in[7];
    float* out = (float*)d_out;

    // ---- workspace layout (~176.6 MB total; proven-safe < 201.8 MB) ----
    float* sq   = (float*)d_ws;                        // [2][384]
    float* attn = sq + 2 * 384;                        // [2][9216]
    bfr*  w_bf  = (bfr*)(attn + 2 * HEADS * CH * CH);  // [576*192]
    bfr*  M_bf  = w_bf + C3 * C;                       // [2][192*192]
    bfr*  xT    = M_bf + 2 * C * C;                    // [2][N*192]  (reused as vT)
    bfr*  vT    = xT;                                  //   alias: xT dead after qkv gemm
    bfr*  qkv   = xT + 2 * N * C;                      // [2][576*N]
    bfr*  dwout = qkv + 2 * CHN;                       // [2][576*N]

    // zero sq + attn (atomic accumulation targets)
    hipMemsetAsync(d_ws, 0, (2 * 384 + 2 * HEADS * CH * CH) * sizeof(float), stream);

    convert_bf<<<(C3 * C / 4 + 255) / 256, 256, 0, stream>>>(qkv_w, w_bf, C3 * C / 4);

    // x -> xT bf16 [n][192] (both batches)
    transpose_cn<float><<<dim3((unsigned)(N / 64), C / 64, 2), 256, 0, stream>>>(
        x, (long)C * N, xT, N * 192L);
    // qkv = W @ x
    gemm_mfma<bfr><<<dim3((unsigned)((N / 128) * (C3 / 64)), 1, 2), 256, 0, stream>>>(
        w_bf, 0L, qkv_b, xT, N * 192L, qkv, CHN, C3 / 64);
    // depthwise conv + sumsq (known-good 10-plane version)
    dwconv3<<<dim3(C3 * 4, 2), 256, 0, stream>>>(qkv, dw_w, dw_b, dwout, sq);
    // v -> vT (into the xT region — xT is dead now)
    transpose_cn<bfr><<<dim3((unsigned)(N / 64), C / 64, 2), 256, 0, stream>>>(
        dwout + 2L * C * N, CHN, vT, N * 192L);
    // gram (full coverage, atomic tail)
    gram_mfma<<<dim3(512, 2), 256, 0, stream>>>(dwout, attn);
    // softmax
    softmax_scale<<<2 * HEADS, 64, 0, stream>>>(attn, sq, temp);
    // M = P @ attn
    build_m<<<dim3(C, 2), 192, 0, stream>>>(proj_w, attn, M_bf);
    // out = M @ v + proj_b
    gemm_mfma<float><<<dim3((unsigned)((N / 128) * (C / 64)), 1, 2), 256, 0, stream>>>(
        M_bf, (long)C * C, proj_b, vT, N * 192L, out, (long)C * N, C / 64);
}

// Round 10
// 315.438 us; speedup vs baseline: 1.0543x; 1.0543x over previous
//
#include <hip/hip_runtime.h>

// Attention_41601053229865 — fused 3D channel attention, bf16-MFMA, batched.
// B=2, C=192 (4 heads x 48), spatial 32^3 = 32768.
// R8 passed (332us). This round: ONE change — dwconv3 compute remap to
// 1(w)x4(d) thread tiles + row stride 35. Breaks the 8-way LDS bank
// conflict (2.7e7) caused by 4-aligned (w,d) tiles: banks (3w+4m)%32 are
// uniform 2-way = free on wave64. Staging logic kept verbatim from the
// proven kernel. (Resubmit: R9 bench was a GPU-acquisition timeout.)

typedef unsigned short bfr;   // raw bf16 storage

constexpr int C = 192, C3 = 576, S = 32, HEADS = 4, CH = 48;
constexpr long N = 32768;            // 32^3
constexpr long CHN = (long)C3 * N;   // 18,874,368
#define EPSN 1e-12f

using short8 = __attribute__((ext_vector_type(8))) short;
using f32x4  = __attribute__((ext_vector_type(4))) float;

__device__ __forceinline__ float bf2f(bfr h) { return __uint_as_float(((unsigned)h) << 16); }
__device__ __forceinline__ bfr f2bf(float f) {
    unsigned u = __float_as_uint(f);
    return (bfr)((u + 0x7fffu + ((u >> 16) & 1u)) >> 16);
}
__device__ __forceinline__ float ld1(const float* p) { return *p; }
__device__ __forceinline__ float ld1(const bfr* p) { return bf2f(*p); }
__device__ __forceinline__ void st1(float* p, float v) { *p = v; }
__device__ __forceinline__ void st1(bfr* p, float v) { *p = f2bf(v); }
__device__ __forceinline__ float4 ld4(const float* p) { return *reinterpret_cast<const float4*>(p); }
__device__ __forceinline__ float4 ld4(const bfr* p) {
    ushort4 u = *reinterpret_cast<const ushort4*>(p);
    float4 r; r.x = bf2f(u.x); r.y = bf2f(u.y); r.z = bf2f(u.z); r.w = bf2f(u.w); return r;
}
__device__ __forceinline__ void ld8f(const bfr* p, float* o) {
    short8 u = *reinterpret_cast<const short8*>(p);
#pragma unroll
    for (int e = 0; e < 8; ++e) o[e] = bf2f((bfr)u[e]);
}

__device__ __forceinline__ f32x4 mfma16(short8 a, short8 b, f32x4 c) {
    return __builtin_amdgcn_mfma_f32_16x16x32_bf16(a, b, c, 0, 0, 0);
}

// ---------------------------------------------------------------------------
__global__ __launch_bounds__(256) void convert_bf(
    const float* __restrict__ in, bfr* __restrict__ out, int n4)
{
    const int i = blockIdx.x * 256 + threadIdx.x;
    if (i < n4) {
        const float4 v = *reinterpret_cast<const float4*>(in + (long)i * 4);
        ushort4 u;
        u.x = f2bf(v.x); u.y = f2bf(v.y); u.z = f2bf(v.z); u.w = f2bf(v.w);
        *reinterpret_cast<ushort4*>(out + (long)i * 4) = u;
    }
}

// ---------------------------------------------------------------------------
// Transpose [192][N] -> [N][192] bf16. 64x64 tiles; blockIdx.z = batch.
template <typename T>
__global__ __launch_bounds__(256) void transpose_cn(
    const T* __restrict__ in, long in_bstride,
    bfr* __restrict__ outT, long out_bstride)
{
    __shared__ float sh[64][65];
    const T* inb = in + blockIdx.z * in_bstride;
    bfr* outb = outT + blockIdx.z * out_bstride;
    const int c0 = blockIdx.y * 64;
    const long n0 = (long)blockIdx.x * 64;
    for (int i = threadIdx.x; i < 64 * 16; i += 256) {
        const int c = i >> 4, n4 = (i & 15) * 4;
        const float4 v = ld4(inb + (long)(c0 + c) * N + n0 + n4);
        sh[c][n4 + 0] = v.x; sh[c][n4 + 1] = v.y;
        sh[c][n4 + 2] = v.z; sh[c][n4 + 3] = v.w;
    }
    __syncthreads();
    const int n = threadIdx.x >> 2, seg = threadIdx.x & 3;
    bfr* dst = outb + (n0 + n) * 192 + c0 + seg * 16;
#pragma unroll
    for (int g = 0; g < 4; ++g) {
        ushort4 u;
        u.x = f2bf(sh[seg * 16 + g * 4 + 0][n]);
        u.y = f2bf(sh[seg * 16 + g * 4 + 1][n]);
        u.z = f2bf(sh[seg * 16 + g * 4 + 2][n]);
        u.w = f2bf(sh[seg * 16 + g * 4 + 3][n]);
        *reinterpret_cast<ushort4*>(dst + g * 4) = u;
    }
}

// ---------------------------------------------------------------------------
// MFMA GEMM: Y[o][n] = bias[o] + sum_k A[o][k]*BT[n][k], K=192. z = batch.
template <typename TY>
__global__ __launch_bounds__(256) void gemm_mfma(
    const bfr* __restrict__ A, long a_bstride,
    const float* __restrict__ bias,
    const bfr* __restrict__ BT, long bt_bstride,
    TY* __restrict__ Y, long y_bstride,
    int OT)
{
    constexpr int KPAD = 104;
    __shared__ short sA[64][KPAD];
    __shared__ short sB[128][KPAD];
    const bfr* Ab = A + blockIdx.z * a_bstride;
    const bfr* BTb = BT + blockIdx.z * bt_bstride;
    TY* Yb = Y + blockIdx.z * y_bstride;
    const int nwg = gridDim.x;
    const int wg = blockIdx.x;
    const int xcd = wg & 7, lin = wg >> 3;
    const int q = nwg >> 3, r = nwg & 7;
    const int swz = (xcd < r ? xcd * (q + 1) : r * (q + 1) + (xcd - r) * q) + lin;
    const int o0 = (swz % OT) * 64;
    const long n0 = (long)(swz / OT) * 128;
    const int tid = threadIdx.x;
    const int wave = tid >> 6, lane = tid & 63;
    const int wm = wave & 1, wn = wave >> 1;
    const int lr = lane & 15, lk = lane >> 4;

    f32x4 acc[2][4] = {};
    for (int kc = 0; kc < 192; kc += 96) {
        for (int i = tid; i < 64 * 12; i += 256) {
            const int row = i / 12, c8 = (i % 12) * 8;
            *reinterpret_cast<short8*>(&sA[row][c8]) =
                *reinterpret_cast<const short8*>(&Ab[(long)(o0 + row) * 192 + kc + c8]);
        }
        for (int i = tid; i < 128 * 12; i += 256) {
            const int row = i / 12, c8 = (i % 12) * 8;
            *reinterpret_cast<short8*>(&sB[row][c8]) =
                *reinterpret_cast<const short8*>(&BTb[(n0 + row) * 192 + kc + c8]);
        }
        __syncthreads();
#pragma unroll
        for (int ks = 0; ks < 3; ++ks) {
            short8 af[2], bf[4];
#pragma unroll
            for (int mi = 0; mi < 2; ++mi)
                af[mi] = *reinterpret_cast<const short8*>(&sA[wm * 32 + mi * 16 + lr][ks * 32 + lk * 8]);
#pragma unroll
            for (int ni = 0; ni < 4; ++ni)
                bf[ni] = *reinterpret_cast<const short8*>(&sB[wn * 64 + ni * 16 + lr][ks * 32 + lk * 8]);
#pragma unroll
            for (int mi = 0; mi < 2; ++mi)
#pragma unroll
                for (int ni = 0; ni < 4; ++ni)
                    acc[mi][ni] = mfma16(af[mi], bf[ni], acc[mi][ni]);
        }
        __syncthreads();
    }
#pragma unroll
    for (int mi = 0; mi < 2; ++mi) {
#pragma unroll
        for (int j = 0; j < 4; ++j) {
            const int o = o0 + wm * 32 + mi * 16 + lk * 4 + j;
            const float bo = bias[o];
#pragma unroll
            for (int ni = 0; ni < 4; ++ni)
                st1(&Yb[(long)o * N + n0 + wn * 64 + ni * 16 + lr], acc[mi][ni][j] + bo);
        }
    }
}

// ---------------------------------------------------------------------------
// Depthwise 3x3x3 conv + bias, fused q/k sumsq. Block = (ch, 8 h-planes);
// grid (2304, 2). Stages 10 fp32 planes in LDS (proven staging), computes
// with 1(w)x4(d) thread tiles over 8 plane-iterations.
// Row stride 35 (odd): scalar-read banks = (3w + 4m) % 32 -> uniform 2-way
// across the wave = conflict-free.
__global__ __launch_bounds__(256) void dwconv3(
    const bfr* __restrict__ in, const float* __restrict__ w,
    const float* __restrict__ bias, bfr* __restrict__ out,
    float* __restrict__ sq)
{
    constexpr int ST = 35;
    __shared__ float sp[10][34][ST];
    const int blk = blockIdx.x;
    const int bb = blockIdx.y;
    const int hg = blk & 3;
    const int ch = blk >> 2;
    const int h0 = hg * 8;
    const bfr* base = in + bb * CHN + (long)ch * N;
    const int tid = threadIdx.x;

    // ---- staging: verbatim from the proven kernel (only ST differs) ----
    for (int r2 = tid; r2 < 320; r2 += 256) {
        const int p = r2 >> 5, ww = r2 & 31;
        const int hh = h0 - 1 + p;
        if (hh >= 0 && hh < 32) {
            const bfr* rp = base + hh * 1024 + ww * 32;
            float vals[32];
            ld8f(rp, vals); ld8f(rp + 8, vals + 8);
            ld8f(rp + 16, vals + 16); ld8f(rp + 24, vals + 24);
#pragma unroll
            for (int e = 0; e < 32; ++e) sp[p][ww + 1][e + 1] = vals[e];
        } else {
#pragma unroll
            for (int e = 0; e < 32; ++e) sp[p][ww + 1][e + 1] = 0.f;
        }
    }
    // halos (d = -1 -> col 0, d = 32 -> col 33; w halos rows 0 and 33)
    for (int r2 = tid; r2 < 340; r2 += 256) {
        const int p = r2 / 34, a = r2 % 34;
        sp[p][a][0] = 0.f; sp[p][a][33] = 0.f;
        sp[p][0][a] = 0.f; sp[p][33][a] = 0.f;
    }
    float wr[27];
#pragma unroll
    for (int j = 0; j < 27; ++j) wr[j] = w[ch * 27 + j];
    const float bs = bias[ch];
    __syncthreads();

    // ---- compute: thread owns (w, d0..d0+3); 8 plane-iterations ----
    const int wrow = tid >> 3;            // 0..31
    const int d0   = (tid & 7) * 4;       // 0,4,...,28
    float ssq = 0.f;
    bfr* outb = out + bb * CHN + (long)ch * N;
#pragma unroll
    for (int lh = 0; lh < 8; ++lh) {
        float acc[4] = {bs, bs, bs, bs};
#pragma unroll
        for (int dh = 0; dh < 3; ++dh) {
#pragma unroll
            for (int dw = 0; dw < 3; ++dw) {
                float win[6];
#pragma unroll
                for (int b = 0; b < 6; ++b)
                    win[b] = sp[lh + dh][wrow + dw][d0 + b];
                const float w0_ = wr[(dh * 3 + dw) * 3 + 0];
                const float w1_ = wr[(dh * 3 + dw) * 3 + 1];
                const float w2_ = wr[(dh * 3 + dw) * 3 + 2];
#pragma unroll
                for (int j = 0; j < 4; ++j)
                    acc[j] += w0_ * win[j] + w1_ * win[j + 1] + w2_ * win[j + 2];
            }
        }
        ushort4 u;
        u.x = f2bf(acc[0]); u.y = f2bf(acc[1]);
        u.z = f2bf(acc[2]); u.w = f2bf(acc[3]);
        *reinterpret_cast<ushort4*>(outb + (h0 + lh) * 1024 + wrow * 32 + d0) = u;
        ssq += acc[0] * acc[0] + acc[1] * acc[1] + acc[2] * acc[2] + acc[3] * acc[3];
    }
    if (ch < 2 * C) {
#pragma unroll
        for (int off = 32; off > 0; off >>= 1) ssq += __shfl_down(ssq, off, 64);
        __shared__ float wsum[4];
        if ((tid & 63) == 0) wsum[tid >> 6] = ssq;
        __syncthreads();
        if (tid == 0) atomicAdd(&sq[bb * 384 + ch], wsum[0] + wsum[1] + wsum[2] + wsum[3]);
    }
}

// ---------------------------------------------------------------------------
// Gram via MFMA — atomicAdd tail, FULL coverage. grid (512, 2).
__global__ __launch_bounds__(256) void gram_mfma(
    const bfr* __restrict__ qk, float* __restrict__ attn)
{
    __shared__ __align__(16) short sm[2][48][264];
    const int bb = blockIdx.y;
    const int h = blockIdx.x & 3;
    const int chunk = blockIdx.x >> 2;           // 0..127
    const long nbase = (long)chunk * 256;
    const bfr* qb = qk + bb * CHN + (long)(h * CH) * N + nbase;
    const bfr* kb = qk + bb * CHN + (long)(C + h * CH) * N + nbase;
    const int tid = threadIdx.x;
    for (int i = tid; i < 1536; i += 256) {
        const int row = i >> 5, c8 = (i & 31) * 8;
        *reinterpret_cast<short8*>(&sm[0][row][c8]) =
            *reinterpret_cast<const short8*>(qb + (long)row * N + c8);
        *reinterpret_cast<short8*>(&sm[1][row][c8]) =
            *reinterpret_cast<const short8*>(kb + (long)row * N + c8);
    }
    __syncthreads();
    const int wave = tid >> 6, lane = tid & 63;
    const int lr = lane & 15, lk = lane >> 4;
    f32x4 acc[3][3] = {};
#pragma unroll
    for (int w2 = 0; w2 < 2; ++w2) {
        const int ks = wave * 2 + w2;
        short8 aq[3], bk[3];
#pragma unroll
        for (int ct = 0; ct < 3; ++ct)
            aq[ct] = *reinterpret_cast<const short8*>(&sm[0][ct * 16 + lr][ks * 32 + lk * 8]);
#pragma unroll
        for (int et = 0; et < 3; ++et)
            bk[et] = *reinterpret_cast<const short8*>(&sm[1][et * 16 + lr][ks * 32 + lk * 8]);
#pragma unroll
        for (int ct = 0; ct < 3; ++ct)
#pragma unroll
            for (int et = 0; et < 3; ++et)
                acc[ct][et] = mfma16(aq[ct], bk[et], acc[ct][et]);
    }
    float* dst = attn + (long)(bb * HEADS + h) * CH * CH;
#pragma unroll
    for (int ct = 0; ct < 3; ++ct)
#pragma unroll
        for (int et = 0; et < 3; ++et)
#pragma unroll
            for (int j = 0; j < 4; ++j)
                atomicAdd(&dst[(ct * 16 + lk * 4 + j) * CH + et * 16 + lr], acc[ct][et][j]);
}

// ---------------------------------------------------------------------------
__global__ __launch_bounds__(64) void softmax_scale(
    float* __restrict__ attn, const float* __restrict__ sq,
    const float* __restrict__ temp)
{
    const int bb = blockIdx.x >> 2, h = blockIdx.x & 3;
    const int c = threadIdx.x;
    if (c >= CH) return;
    const float* sqb = sq + bb * 384;
    const float invq = 1.0f / fmaxf(sqrtf(sqb[h * CH + c]), EPSN);
    const float t = temp[h];
    float* row = attn + bb * HEADS * CH * CH + ((long)h * CH + c) * CH;
    float vals[CH];
    float mx = -3.4e38f;
#pragma unroll
    for (int e = 0; e < CH; ++e) {
        const float invk = 1.0f / fmaxf(sqrtf(sqb[C + h * CH + e]), EPSN);
        const float v = row[e] * invq * invk * t;
        vals[e] = v;
        mx = fmaxf(mx, v);
    }
    float sum = 0.f;
#pragma unroll
    for (int e = 0; e < CH; ++e) { vals[e] = expf(vals[e] - mx); sum += vals[e]; }
    const float inv = 1.0f / sum;
#pragma unroll
    for (int e = 0; e < CH; ++e) row[e] = vals[e] * inv;
}

// ---------------------------------------------------------------------------
__global__ __launch_bounds__(192) void build_m(
    const float* __restrict__ P, const float* __restrict__ attn,
    bfr* __restrict__ M)
{
    const int bb = blockIdx.y;
    const int o = blockIdx.x;
    const int he = threadIdx.x;
    const int h = he / CH, e = he % CH;
    const float* attb = attn + bb * HEADS * CH * CH;
    float s = 0.f;
#pragma unroll
    for (int cc = 0; cc < CH; ++cc)
        s += P[o * C + h * CH + cc] * attb[((long)h * CH + cc) * CH + e];
    M[(long)bb * C * C + (long)o * C + he] = f2bf(s);
}

// ---------------------------------------------------------------------------
extern "C" void kernel_launch(void* const* d_in, const int* in_sizes, int n_in,
                              void* d_out, int out_size, void* d_ws, size_t ws_size,
                              hipStream_t stream)
{
    const float* x      = (const float*)d_in[0];
    const float* qkv_w  = (const float*)d_in[1];
    const float* qkv_b  = (const float*)d_in[2];
    const float* dw_w   = (const float*)d_in[3];
    const float* dw_b   = (const float*)d_in[4];
    const float* proj_w = (const float*)d_in[5];
    const float* proj_b = (const float*)d_in[6];
    const float* temp   = (const float*)d_in[7];
    float* out = (float*)d_out;

    // ---- workspace layout (~176.6 MB total; proven-safe < 201.8 MB) ----
    float* sq   = (float*)d_ws;                        // [2][384]
    float* attn = sq + 2 * 384;                        // [2][9216]
    bfr*  w_bf  = (bfr*)(attn + 2 * HEADS * CH * CH);  // [576*192]
    bfr*  M_bf  = w_bf + C3 * C;                       // [2][192*192]
    bfr*  xT    = M_bf + 2 * C * C;                    // [2][N*192]  (reused as vT)
    bfr*  vT    = xT;                                  //   alias: xT dead after qkv gemm
    bfr*  qkv   = xT + 2 * N * C;                      // [2][576*N]
    bfr*  dwout = qkv + 2 * CHN;                       // [2][576*N]

    // zero sq + attn (atomic accumulation targets)
    hipMemsetAsync(d_ws, 0, (2 * 384 + 2 * HEADS * CH * CH) * sizeof(float), stream);

    convert_bf<<<(C3 * C / 4 + 255) / 256, 256, 0, stream>>>(qkv_w, w_bf, C3 * C / 4);

    // x -> xT bf16 [n][192] (both batches)
    transpose_cn<float><<<dim3((unsigned)(N / 64), C / 64, 2), 256, 0, stream>>>(
        x, (long)C * N, xT, N * 192L);
    // qkv = W @ x
    gemm_mfma<bfr><<<dim3((unsigned)((N / 128) * (C3 / 64)), 1, 2), 256, 0, stream>>>(
        w_bf, 0L, qkv_b, xT, N * 192L, qkv, CHN, C3 / 64);
    // depthwise conv + sumsq (conflict-free remap)
    dwconv3<<<dim3(C3 * 4, 2), 256, 0, stream>>>(qkv, dw_w, dw_b, dwout, sq);
    // v -> vT (into the xT region — xT is dead now)
    transpose_cn<bfr><<<dim3((unsigned)(N / 64), C / 64, 2), 256, 0, stream>>>(
        dwout + 2L * C * N, CHN, vT, N * 192L);
    // gram (full coverage, atomic tail)
    gram_mfma<<<dim3(512, 2), 256, 0, stream>>>(dwout, attn);
    // softmax
    softmax_scale<<<2 * HEADS, 64, 0, stream>>>(attn, sq, temp);
    // M = P @ attn
    build_m<<<dim3(C, 2), 192, 0, stream>>>(proj_w, attn, M_bf);
    // out = M @ v + proj_b
    gemm_mfma<float><<<dim3((unsigned)((N / 128) * (C / 64)), 1, 2), 256, 0, stream>>>(
        M_bf, (long)C * C, proj_b, vT, N * 192L, out, (long)C * N, C / 64);
}